// Round 9
// baseline (140.126 us; speedup 1.0000x reference)
//
#include <hip/hip_runtime.h>

// GaussianSplatter: out[(bl,c),(y,x)] = clip( sum_p A[(bl,c),p] * KY[p,y]*KX[p,x] )
// M=4096 (=64 patches * 64 ch), N=2304 (=48*48 pixels), K=2304 (=48*48 points)
// R9: R6 resurrected with the root-caused fix: band-Kt rows need up to 1376 halves
//     (tt=7/10), was 1344 -> now 176 chunks/row. GEMM = R6's A-direct (verified):
//     A staged from f32 inp (reg->cvt->swizzled ds_write), B via pre-swizzled
//     gload_lds (R4-proven), XOR-swizzled LDS (0 conflicts), XCD-chunked swizzle.

#define NPTS 2304
#define KD   2304
#define HH   192

typedef _Float16 f16;
typedef _Float16 f16x4 __attribute__((ext_vector_type(4)));
typedef _Float16 f16x8 __attribute__((ext_vector_type(8)));
typedef float f32x4 __attribute__((ext_vector_type(4)));

__device__ __forceinline__ void gload16(const f16* g, f16* l) {
    __builtin_amdgcn_global_load_lds((const __attribute__((address_space(1))) void*)g,
                                     (__attribute__((address_space(3))) void*)l,
                                     16, 0, 0);
}

// shared k-window: i-band of n-tile tt (pixels tt*128 .. tt*128+127)
// max window = 28 i-rows * 48 + 32 rounding = 1376 halves (tt=7,10) -> 172 chunks; use 176.
__device__ __forceinline__ void kwindow(int tt, int& k_lo, int& k_hi) {
    int n0 = tt * 128;
    int y_min = n0 / 48;
    int y_max = (n0 + 127) / 48;
    int i_lo = max(0,  (int)floorf((y_min - 10.5f) * (48.0f / 47.0f)));
    int i_hi = min(47, (int)ceilf ((y_max + 11.5f) * (48.0f / 47.0f)));
    k_lo = (i_lo * 48) & ~31;
    k_hi = min(KD, ((i_hi + 1) * 48 + 31) & ~31);
}

// one bilinear tap of the padded 1-D gaussian: taps t in [13,33] hold exp(-(0.5t-11.5)^2 * inv2s)
__device__ __forceinline__ float gtap(float t, float inv2s) {
    float ax = 0.5f * t - 11.5f;
    float g = expf(-ax * ax * inv2s);
    return (t >= 12.5f && t <= 33.5f) ? g : 0.0f;
}

// KY_T[y][p] (opacity folded), KX_T[x][p]  -- R1-verbatim (passed)
__global__ void build_tabs(const float* __restrict__ sx, const float* __restrict__ sy,
                           const float* __restrict__ op,
                           float* __restrict__ KY_T, float* __restrict__ KX_T) {
    int flat = blockIdx.x * 256 + threadIdx.x;      // 48*2304 = 110592
    if (flat >= 48 * NPTS) return;
    int pos = flat / NPTS;
    int p   = flat - pos * NPTS;
    int i = p / 48;
    int j = p - i * 48;
    float sxv = sx[p], syv = sy[p], opv = op[p];
    float invx = 0.5f / (sxv * sxv);  // h-axis uses sigma_x (reference: xx2/sx2 on axis 1)
    float invy = 0.5f / (syv * syv);

    float py = (float)pos + 23.5f - (47.0f / 48.0f) * (float)i;
    float y0 = floorf(py), fy = py - y0;
    KY_T[flat] = opv * (gtap(y0, invx) * (1.0f - fy) + gtap(y0 + 1.0f, invx) * fy);

    float px = (float)pos + 23.5f - (47.0f / 48.0f) * (float)j;
    float x0 = floorf(px), fx = px - x0;
    KX_T[flat] = gtap(x0, invy) * (1.0f - fx) + gtap(x0 + 1.0f, invy) * fx;
}

// Band-only Kt: row hw gets exactly [k_lo(tt), k_hi(tt)), tt = hw>>7 -- the precise
// range gemm reads. 176 chunks/row (window provably <= 1376 halves = 172 chunks).
__global__ void build_kt(const float* __restrict__ KY_T, const float* __restrict__ KX_T,
                         f16* __restrict__ Kt) {
    int idx = blockIdx.x * 256 + threadIdx.x;       // 2304*176 = 405504
    int hw = idx / 176;
    int ci = idx - hw * 176;
    int k_lo, k_hi;
    kwindow(hw >> 7, k_lo, k_hi);
    int p0 = k_lo + ci * 8;
    if (p0 >= k_hi) return;
    int y = hw / 48, x = hw - y * 48;
    const float4* ky = (const float4*)(KY_T + (size_t)y * NPTS + p0);
    const float4* kx = (const float4*)(KX_T + (size_t)x * NPTS + p0);
    float4 a0 = ky[0], a1 = ky[1];
    float4 b0 = kx[0], b1 = kx[1];
    f16x8 r;
    r[0] = (f16)(a0.x * b0.x); r[1] = (f16)(a0.y * b0.y);
    r[2] = (f16)(a0.z * b0.z); r[3] = (f16)(a0.w * b0.w);
    r[4] = (f16)(a1.x * b1.x); r[5] = (f16)(a1.y * b1.y);
    r[6] = (f16)(a1.z * b1.z); r[7] = (f16)(a1.w * b1.w);
    *(f16x8*)(Kt + (size_t)hw * NPTS + p0) = r;
}

// C[m][n] = sum_k A[m][k] * Bt[n][k]; A read directly from inp (f32->f16 on the fly).
// LDS swizzle: slot (row, chunk cs) holds global k-chunk cs ^ ((row>>1)&3).
//   B: inverse baked into gload_lds source offsets (rule 21 / m173, R4-proven).
//   A: applied at ds_write (write chunk = cs ^ key, key = (row>>1)&3 = lane>>4).
__global__ __launch_bounds__(256) void gemm_splat(const float* __restrict__ inp,
                                                  const f16* __restrict__ Bt,
                                                  float* __restrict__ out) {
    __shared__ __attribute__((aligned(16))) f16 As[2 * 4096];   // [2][128][32]
    __shared__ __attribute__((aligned(16))) f16 Bs[2 * 4096];   // [2][128][32]

    int tid  = threadIdx.x;
    int lane = tid & 63;
    int w    = tid >> 6;
    int wr   = w >> 1, wc = w & 1;       // wave -> (64,64) output quadrant
    // XCD-chunked bijective swizzle: 576 blocks = 8 XCDs x 72 (= 4 m-panels x 18 n-tiles)
    int bx   = blockIdx.x;
    int wg   = (bx & 7) * 72 + (bx >> 3);
    int m0   = (wg / 18) * 128;
    int tt   = wg % 18;
    int n0   = tt * 128;

    int k_lo, k_hi;
    kwindow(tt, k_lo, k_hi);
    int nt = (k_hi - k_lo) >> 5;

    // ---- B staging (gload_lds, pre-swizzled source; R4-proven) ----
    int srow = lane >> 2;
    int sk   = (((lane & 3) ^ ((lane >> 3) & 3)) << 3);
    const f16* Bbase = Bt + (size_t)(n0 + w * 32 + srow) * KD + sk + k_lo;

    // ---- A staging from inp: wave w covers LDS rows w*32..w*32+31 (m = m0 + row) ----
    int bl = (m0 >> 6) + (w >> 1);
    int b = bl >> 4, pr = (bl >> 2) & 3, pc = bl & 3;
    const float* ibase = inp + ((size_t)(b * 64) * HH + pr * 48) * HH + pc * 48;
    int c0 = (w & 1) * 32 + (lane >> 3);
    const float* pA0 = ibase + (size_t)c0 * (HH * HH);
    // per-lane k: k = k_lo + t*32 + (lane&7)*4 ; 4-float chunk never crosses an input row
    int kl = k_lo + (lane & 7) * 4;
    int ii = kl / 48;
    int jj = kl - ii * 48;
    int off = ii * HH + jj;
    // LDS write offset (halves): row*32 + (chunk ^ key)*8 + (lane&1)*4, key = lane>>4
    int aw = (w * 32 + (lane >> 3)) * 32 + ((((lane >> 1) & 3) ^ (lane >> 4)) << 3) + (lane & 1) * 4;

    // fragment reads: row = 16q + lrow; swizzled chunk = (lane>>4) ^ ((lrow>>1)&3)
    int lrow = lane & 15;
    int koe  = (((lane >> 4) ^ ((lane >> 1) & 3)) << 3);

    f32x4 acc[4][4] = {};
    float4 av0, av1, av2, av3;

    #define ALOAD()                                             \
        do {                                                    \
            av0 = *(const float4*)(pA0 + off);                  \
            av1 = *(const float4*)(pA0 +  8 * HH * HH + off);   \
            av2 = *(const float4*)(pA0 + 16 * HH * HH + off);   \
            av3 = *(const float4*)(pA0 + 24 * HH * HH + off);   \
        } while (0)
    #define AWRITE(slot)                                                          \
        do {                                                                      \
            f16* as_ = &As[(slot) * 4096 + aw];                                   \
            f16x4 h;                                                              \
            h[0]=(f16)av0.x; h[1]=(f16)av0.y; h[2]=(f16)av0.z; h[3]=(f16)av0.w;   \
            *(f16x4*)(as_      ) = h;                                             \
            h[0]=(f16)av1.x; h[1]=(f16)av1.y; h[2]=(f16)av1.z; h[3]=(f16)av1.w;   \
            *(f16x4*)(as_ + 256) = h;                                             \
            h[0]=(f16)av2.x; h[1]=(f16)av2.y; h[2]=(f16)av2.z; h[3]=(f16)av2.w;   \
            *(f16x4*)(as_ + 512) = h;                                             \
            h[0]=(f16)av3.x; h[1]=(f16)av3.y; h[2]=(f16)av3.z; h[3]=(f16)av3.w;   \
            *(f16x4*)(as_ + 768) = h;                                             \
        } while (0)
    #define AADV()                                              \
        do {                                                    \
            int jn = jj + 32;                                   \
            int ov = (jn >= 48);                                \
            off += ov ? (HH - 48 + 32) : 32;                    \
            jj  = ov ? jn - 48 : jn;                            \
        } while (0)

    // prologue: stage tile 0 into slot 0
    ALOAD();
    gload16(Bbase,           &Bs[w * 1024]);
    gload16(Bbase + 16 * KD, &Bs[w * 1024 + 512]);
    AWRITE(0);
    AADV();
    __syncthreads();

    for (int t = 0; t < nt; ++t) {
        int cur = t & 1;
        bool more = (t + 1 < nt);
        if (more) {
            ALOAD();                                            // A(t+1) -> regs (in flight)
            gload16(Bbase + ((t + 1) << 5),           &Bs[(cur ^ 1) * 4096 + w * 1024]);
            gload16(Bbase + 16 * KD + ((t + 1) << 5), &Bs[(cur ^ 1) * 4096 + w * 1024 + 512]);
        }

        f16x8 af[4], bf[4];
        #pragma unroll
        for (int mi = 0; mi < 4; ++mi)
            af[mi] = *(const f16x8*)&As[cur * 4096 + (wr * 64 + mi * 16 + lrow) * 32 + koe];
        #pragma unroll
        for (int ni = 0; ni < 4; ++ni)
            bf[ni] = *(const f16x8*)&Bs[cur * 4096 + (wc * 64 + ni * 16 + lrow) * 32 + koe];

        __builtin_amdgcn_s_setprio(1);
        #pragma unroll
        for (int mi = 0; mi < 4; ++mi)
            #pragma unroll
            for (int ni = 0; ni < 4; ++ni)
                acc[mi][ni] = __builtin_amdgcn_mfma_f32_16x16x32_f16(af[mi], bf[ni], acc[mi][ni], 0, 0, 0);
        __builtin_amdgcn_s_setprio(0);

        if (more) {
            AWRITE(cur ^ 1);                                    // cvt + swizzled scatter after MFMA
            AADV();
        }
        __syncthreads();
    }
    #undef ALOAD
    #undef AWRITE
    #undef AADV

    // epilogue: D row = (lane>>4)*4 + r, col = lane&15 (m89-verified C/D layout); clip + fold
    #pragma unroll
    for (int mi = 0; mi < 4; ++mi) {
        #pragma unroll
        for (int r = 0; r < 4; ++r) {
            int m  = m0 + wr * 64 + mi * 16 + (lane >> 4) * 4 + r;
            int blm = m >> 6, c = m & 63;
            int bb  = blm >> 4, prm = (blm >> 2) & 3, pcm = blm & 3;
            float* orow = out + ((size_t)(bb * 64 + c) * HH + prm * 48) * HH + pcm * 48;
            #pragma unroll
            for (int ni = 0; ni < 4; ++ni) {
                int n = n0 + wc * 64 + ni * 16 + (lane & 15);
                int y = n / 48, x = n - y * 48;
                float v = acc[mi][ni][r];
                v = fminf(fmaxf(v, 0.0f), 1.0f);
                orow[y * HH + x] = v;
            }
        }
    }
}

extern "C" void kernel_launch(void* const* d_in, const int* in_sizes, int n_in,
                              void* d_out, int out_size, void* d_ws, size_t ws_size,
                              hipStream_t stream) {
    const float* inp = (const float*)d_in[0];
    const float* sx  = (const float*)d_in[1];
    const float* sy  = (const float*)d_in[2];
    const float* op  = (const float*)d_in[3];
    float* out = (float*)d_out;

    char* ws = (char*)d_ws;
    float* KY_T = (float*)ws;                         //   442368 B
    float* KX_T = (float*)(ws + 442368);              //   442368 B
    f16*   Kt   = (f16*)(ws + 884736);                // 10616832 B  [2304][2304] (band rows)

    build_tabs<<<dim3(432),  dim3(256), 0, stream>>>(sx, sy, op, KY_T, KX_T);
    build_kt  <<<dim3(1584), dim3(256), 0, stream>>>(KY_T, KX_T, Kt);
    gemm_splat<<<dim3(576),  dim3(256), 0, stream>>>(inp, Kt, out);
}

// Round 10
// 132.099 us; speedup vs baseline: 1.0608x; 1.0608x over previous
//
#include <hip/hip_runtime.h>

// GaussianSplatter: out[(bl,c),(y,x)] = clip( sum_p A[(bl,c),p] * KY[p,y]*KX[p,x] )
// M=4096 (=64 patches * 64 ch), N=2304 (=48*48 pixels), K=2304 (=48*48 points)
// R10: consolidation of proven pieces. GEMM = R8 verbatim (gload_lds A+B, depth-3,
//      counted vmcnt, 0-conflict XOR swizzle, XCD swizzle). Prep = ONE kernel:
//      band-only Kt (inline gaussians, 176 chunks/row — R9-proven sizing) + pack_A.

#define NPTS 2304
#define KD   2304
#define HH   192

typedef _Float16 f16;
typedef _Float16 f16x8 __attribute__((ext_vector_type(8)));
typedef float f32x4 __attribute__((ext_vector_type(4)));

__device__ __forceinline__ void gload16(const f16* g, f16* l) {
    __builtin_amdgcn_global_load_lds((const __attribute__((address_space(1))) void*)g,
                                     (__attribute__((address_space(3))) void*)l,
                                     16, 0, 0);
}

// shared k-window: i-band of n-tile tt (pixels tt*128 .. tt*128+127)
// max window = 28 i-rows * 48 + both-sided 32-alignment = 1376 halves -> 172 chunks; use 176.
__device__ __forceinline__ void kwindow(int tt, int& k_lo, int& k_hi) {
    int n0 = tt * 128;
    int y_min = n0 / 48;
    int y_max = (n0 + 127) / 48;
    int i_lo = max(0,  (int)floorf((y_min - 10.5f) * (48.0f / 47.0f)));
    int i_hi = min(47, (int)ceilf ((y_max + 11.5f) * (48.0f / 47.0f)));
    k_lo = (i_lo * 48) & ~31;
    k_hi = min(KD, ((i_hi + 1) * 48 + 31) & ~31);
}

// one bilinear tap of the padded 1-D gaussian: taps t in [13,33] hold exp(-(0.5t-11.5)^2 * inv2s)
__device__ __forceinline__ float gtap(float t, float inv2s) {
    float ax = 0.5f * t - 11.5f;
    float g = expf(-ax * ax * inv2s);
    return (t >= 12.5f && t <= 33.5f) ? g : 0.0f;
}

// Fused prep: blocks [0,1584) band-only Kt (inline gaussians, R4/R5-proven math);
//             blocks [1584,6192) pack_A (proven verbatim).
__global__ void prep(const float* __restrict__ inp,
                     const float* __restrict__ sx, const float* __restrict__ sy,
                     const float* __restrict__ op,
                     f16* __restrict__ Kt, f16* __restrict__ Ap) {
    int bid = blockIdx.x;
    if (bid < 1584) {
        // band-only Kt: row hw gets exactly [k_lo(tt), k_hi(tt)), tt = hw>>7
        int idx = bid * 256 + threadIdx.x;          // 2304*176 = 405504 = 1584*256
        int hw = idx / 176;
        int ci = idx - hw * 176;
        int k_lo, k_hi;
        kwindow(hw >> 7, k_lo, k_hi);
        int p0 = k_lo + ci * 8;
        if (p0 >= k_hi) return;
        int y = hw / 48, x = hw - y * 48;
        int i = p0 / 48, j0 = p0 - i * 48;          // p0 8-aligned -> chunk stays in row i
        float py = (float)y + 23.5f - (47.0f / 48.0f) * (float)i;
        float y0 = floorf(py), fy = py - y0;
        f16x8 r;
        #pragma unroll
        for (int u = 0; u < 8; ++u) {
            int p = p0 + u;
            float sxv = sx[p], syv = sy[p], opv = op[p];
            float invx = 0.5f / (sxv * sxv);  // h-axis uses sigma_x (ref: xx2/sx2 on axis 1)
            float invy = 0.5f / (syv * syv);
            float ky = opv * (gtap(y0, invx) * (1.0f - fy) + gtap(y0 + 1.0f, invx) * fy);
            float px = (float)x + 23.5f - (47.0f / 48.0f) * (float)(j0 + u);
            float x0 = floorf(px), fx = px - x0;
            float kx = gtap(x0, invy) * (1.0f - fx) + gtap(x0 + 1.0f, invy) * fx;
            r[u] = (f16)(ky * kx);
        }
        *(f16x8*)(Kt + (size_t)hw * NPTS + p0) = r;
    } else {
        // pack_A: A[m][p] fp16, m = bl*64+c, p = i*48+j
        int idx = (bid - 1584) * 256 + threadIdx.x; // 4096*288 chunks
        int m = idx / 288;
        int p0 = (idx - m * 288) * 8;
        int i = p0 / 48, j = p0 - i * 48;           // 8-chunk never crosses a patch row
        int bl = m >> 6, c = m & 63;
        int b = bl >> 4, pr = (bl >> 2) & 3, pc = bl & 3;
        const float* src = inp + ((size_t)(b * 64 + c) * HH + pr * 48 + i) * HH + pc * 48 + j;
        float4 a0 = *(const float4*)src;
        float4 a1 = *(const float4*)(src + 4);
        f16x8 r;
        r[0] = (f16)a0.x; r[1] = (f16)a0.y; r[2] = (f16)a0.z; r[3] = (f16)a0.w;
        r[4] = (f16)a1.x; r[5] = (f16)a1.y; r[6] = (f16)a1.z; r[7] = (f16)a1.w;
        *(f16x8*)(Ap + (size_t)m * KD + p0) = r;
    }
}

// C[m][n] = sum_k A[m][k] * Bt[n][k], k restricted to the i-band of this n-tile.
// R8-verbatim (passed, <44us): XOR-swizzled LDS (0 conflicts), depth-3, counted vmcnt.
__global__ __launch_bounds__(256) void gemm_splat(const f16* __restrict__ A,
                                                  const f16* __restrict__ Bt,
                                                  float* __restrict__ out) {
    __shared__ __attribute__((aligned(16))) f16 As[3 * 4096];   // [3][128][32]
    __shared__ __attribute__((aligned(16))) f16 Bs[3 * 4096];   // [3][128][32]

    int tid  = threadIdx.x;
    int lane = tid & 63;
    int w    = tid >> 6;
    int wr   = w >> 1, wc = w & 1;       // wave -> (64,64) output quadrant
    // XCD-chunked bijective swizzle: 576 blocks = 8 XCDs x 72 (= 4 m-panels x 18 n-tiles)
    int bx   = blockIdx.x;
    int wg   = (bx & 7) * 72 + (bx >> 3);
    int m0   = (wg / 18) * 128;
    int tt   = wg % 18;
    int n0   = tt * 128;

    int k_lo, k_hi;
    kwindow(tt, k_lo, k_hi);
    int nt = (k_hi - k_lo) >> 5;

    // staging: per inst 16 rows x 4 chunks; lane -> row lane>>2, chunk lane&3,
    // source k-chunk pre-swizzled by row-pair key (lane>>3)&3
    int srow = lane >> 2;
    int sk   = (((lane & 3) ^ ((lane >> 3) & 3)) << 3);
    const f16* Abase = A  + (size_t)(m0 + w * 32 + srow) * KD + sk + k_lo;
    const f16* Bbase = Bt + (size_t)(n0 + w * 32 + srow) * KD + sk + k_lo;

    // fragment reads: row = 16*q + lrow; swizzled chunk = (lane>>4) ^ ((lrow>>1)&3)
    int lrow = lane & 15;
    int koe  = (((lane >> 4) ^ ((lane >> 1) & 3)) << 3);

    f32x4 acc[4][4] = {};

    // 4 gload16 per wave per stage -> counted wait vmcnt(4) keeps newest stage in flight
    #define STAGE(slot, koff)                                                   \
        do {                                                                    \
            f16* as_ = &As[(slot) * 4096 + w * 1024];                           \
            f16* bs_ = &Bs[(slot) * 4096 + w * 1024];                           \
            gload16(Abase + (koff),           as_);                             \
            gload16(Abase + 16 * KD + (koff), as_ + 512);                       \
            gload16(Bbase + (koff),           bs_);                             \
            gload16(Bbase + 16 * KD + (koff), bs_ + 512);                       \
        } while (0)

    // prologue: stage tiles 0,1; retire tile 0 (8 outstanding -> wait 4)
    STAGE(0, 0);
    STAGE(1, 32);
    asm volatile("s_waitcnt vmcnt(4)" ::: "memory");
    __builtin_amdgcn_s_barrier();
    __builtin_amdgcn_sched_barrier(0);

    int rs = 0, ps = 2;   // read slot t%3; stage slot (t+2)%3 == previous read slot
    for (int t = 0; t < nt; ++t) {
        if (t + 2 < nt) STAGE(ps, (t + 2) << 5);

        const f16* as_ = &As[rs * 4096];
        const f16* bs_ = &Bs[rs * 4096];
        f16x8 af[4], bf[4];
        #pragma unroll
        for (int mi = 0; mi < 4; ++mi)
            af[mi] = *(const f16x8*)&as_[(wr * 64 + mi * 16 + lrow) * 32 + koe];
        #pragma unroll
        for (int ni = 0; ni < 4; ++ni)
            bf[ni] = *(const f16x8*)&bs_[(wc * 64 + ni * 16 + lrow) * 32 + koe];

        __builtin_amdgcn_s_setprio(1);
        #pragma unroll
        for (int mi = 0; mi < 4; ++mi)
            #pragma unroll
            for (int ni = 0; ni < 4; ++ni)
                acc[mi][ni] = __builtin_amdgcn_mfma_f32_16x16x32_f16(af[mi], bf[ni], acc[mi][ni], 0, 0, 0);
        __builtin_amdgcn_s_setprio(0);

        // retire tile t+1 before the barrier; keep tile t+2's loads in flight
        if (t + 2 < nt) {
            asm volatile("s_waitcnt vmcnt(4)" ::: "memory");
        } else if (t + 1 < nt) {
            asm volatile("s_waitcnt vmcnt(0)" ::: "memory");
        }
        if (t + 1 < nt) {
            __builtin_amdgcn_s_barrier();
            __builtin_amdgcn_sched_barrier(0);
        }
        ps = rs;
        rs = (rs == 2) ? 0 : rs + 1;
    }
    #undef STAGE

    // epilogue: D row = (lane>>4)*4 + r, col = lane&15 (m89-verified C/D layout); clip + fold
    #pragma unroll
    for (int mi = 0; mi < 4; ++mi) {
        #pragma unroll
        for (int r = 0; r < 4; ++r) {
            int m  = m0 + wr * 64 + mi * 16 + (lane >> 4) * 4 + r;
            int bl = m >> 6, c = m & 63;
            int b  = bl >> 4, pr = (bl >> 2) & 3, pc = bl & 3;
            float* orow = out + ((size_t)(b * 64 + c) * HH + pr * 48) * HH + pc * 48;
            #pragma unroll
            for (int ni = 0; ni < 4; ++ni) {
                int n = n0 + wc * 64 + ni * 16 + (lane & 15);
                int y = n / 48, x = n - y * 48;
                float v = acc[mi][ni][r];
                v = fminf(fmaxf(v, 0.0f), 1.0f);
                orow[y * HH + x] = v;
            }
        }
    }
}

extern "C" void kernel_launch(void* const* d_in, const int* in_sizes, int n_in,
                              void* d_out, int out_size, void* d_ws, size_t ws_size,
                              hipStream_t stream) {
    const float* inp = (const float*)d_in[0];
    const float* sx  = (const float*)d_in[1];
    const float* sy  = (const float*)d_in[2];
    const float* op  = (const float*)d_in[3];
    float* out = (float*)d_out;

    char* ws = (char*)d_ws;
    f16* Kt = (f16*)ws;                      // 10616832 B  [2304][2304] (band rows only)
    f16* Ap = (f16*)(ws + 10616832);         // 18874368 B  [4096][2304]

    prep      <<<dim3(6192), dim3(256), 0, stream>>>(inp, sx, sy, op, Kt, Ap);
    gemm_splat<<<dim3(576),  dim3(256), 0, stream>>>(Ap, Kt, out);
}

// Round 11
// 131.611 us; speedup vs baseline: 1.0647x; 1.0037x over previous
//
#include <hip/hip_runtime.h>

// GaussianSplatter: out[(bl,c),(y,x)] = clip( sum_p A[(bl,c),p] * KY[p,y]*KX[p,x] )
// M=4096 (=64 patches * 64 ch), N=2304 (=48*48 pixels), K=2304 (=48*48 points)
// R11 = R10 with ONE change: gemm goes 4 waves -> 8 waves per block (512 thr),
//      each wave 32x64 output (acc[2][4]), staging 2 gload16/wave, counted vmcnt(2).
//      Same 128^2 tile, same XOR swizzle (key invariant), same depth-3 slots.

#define NPTS 2304
#define KD   2304
#define HH   192

typedef _Float16 f16;
typedef _Float16 f16x8 __attribute__((ext_vector_type(8)));
typedef float f32x4 __attribute__((ext_vector_type(4)));

__device__ __forceinline__ void gload16(const f16* g, f16* l) {
    __builtin_amdgcn_global_load_lds((const __attribute__((address_space(1))) void*)g,
                                     (__attribute__((address_space(3))) void*)l,
                                     16, 0, 0);
}

// shared k-window: i-band of n-tile tt (pixels tt*128 .. tt*128+127)
// max window = 28 i-rows * 48 + both-sided 32-alignment = 1376 halves -> 172 chunks; use 176.
__device__ __forceinline__ void kwindow(int tt, int& k_lo, int& k_hi) {
    int n0 = tt * 128;
    int y_min = n0 / 48;
    int y_max = (n0 + 127) / 48;
    int i_lo = max(0,  (int)floorf((y_min - 10.5f) * (48.0f / 47.0f)));
    int i_hi = min(47, (int)ceilf ((y_max + 11.5f) * (48.0f / 47.0f)));
    k_lo = (i_lo * 48) & ~31;
    k_hi = min(KD, ((i_hi + 1) * 48 + 31) & ~31);
}

// one bilinear tap of the padded 1-D gaussian: taps t in [13,33] hold exp(-(0.5t-11.5)^2 * inv2s)
__device__ __forceinline__ float gtap(float t, float inv2s) {
    float ax = 0.5f * t - 11.5f;
    float g = expf(-ax * ax * inv2s);
    return (t >= 12.5f && t <= 33.5f) ? g : 0.0f;
}

// Fused prep: blocks [0,1584) band-only Kt (inline gaussians, R10-proven);
//             blocks [1584,6192) pack_A (proven verbatim).
__global__ void prep(const float* __restrict__ inp,
                     const float* __restrict__ sx, const float* __restrict__ sy,
                     const float* __restrict__ op,
                     f16* __restrict__ Kt, f16* __restrict__ Ap) {
    int bid = blockIdx.x;
    if (bid < 1584) {
        // band-only Kt: row hw gets exactly [k_lo(tt), k_hi(tt)), tt = hw>>7
        int idx = bid * 256 + threadIdx.x;          // 2304*176 = 405504 = 1584*256
        int hw = idx / 176;
        int ci = idx - hw * 176;
        int k_lo, k_hi;
        kwindow(hw >> 7, k_lo, k_hi);
        int p0 = k_lo + ci * 8;
        if (p0 >= k_hi) return;
        int y = hw / 48, x = hw - y * 48;
        int i = p0 / 48, j0 = p0 - i * 48;          // p0 8-aligned -> chunk stays in row i
        float py = (float)y + 23.5f - (47.0f / 48.0f) * (float)i;
        float y0 = floorf(py), fy = py - y0;
        f16x8 r;
        #pragma unroll
        for (int u = 0; u < 8; ++u) {
            int p = p0 + u;
            float sxv = sx[p], syv = sy[p], opv = op[p];
            float invx = 0.5f / (sxv * sxv);  // h-axis uses sigma_x (ref: xx2/sx2 on axis 1)
            float invy = 0.5f / (syv * syv);
            float ky = opv * (gtap(y0, invx) * (1.0f - fy) + gtap(y0 + 1.0f, invx) * fy);
            float px = (float)x + 23.5f - (47.0f / 48.0f) * (float)(j0 + u);
            float x0 = floorf(px), fx = px - x0;
            float kx = gtap(x0, invy) * (1.0f - fx) + gtap(x0 + 1.0f, invy) * fx;
            r[u] = (f16)(ky * kx);
        }
        *(f16x8*)(Kt + (size_t)hw * NPTS + p0) = r;
    } else {
        // pack_A: A[m][p] fp16, m = bl*64+c, p = i*48+j
        int idx = (bid - 1584) * 256 + threadIdx.x; // 4096*288 chunks
        int m = idx / 288;
        int p0 = (idx - m * 288) * 8;
        int i = p0 / 48, j = p0 - i * 48;           // 8-chunk never crosses a patch row
        int bl = m >> 6, c = m & 63;
        int b = bl >> 4, pr = (bl >> 2) & 3, pc = bl & 3;
        const float* src = inp + ((size_t)(b * 64 + c) * HH + pr * 48 + i) * HH + pc * 48 + j;
        float4 a0 = *(const float4*)src;
        float4 a1 = *(const float4*)(src + 4);
        f16x8 r;
        r[0] = (f16)a0.x; r[1] = (f16)a0.y; r[2] = (f16)a0.z; r[3] = (f16)a0.w;
        r[4] = (f16)a1.x; r[5] = (f16)a1.y; r[6] = (f16)a1.z; r[7] = (f16)a1.w;
        *(f16x8*)(Ap + (size_t)m * KD + p0) = r;
    }
}

// C[m][n] = sum_k A[m][k] * Bt[n][k], k restricted to the i-band of this n-tile.
// 8 waves, wave = 32x64 output quadrant. XOR-swizzled LDS (0 conflicts), depth-3 slots,
// counted vmcnt(2). Swizzle key (row>>1)&3 == (lane>>3)&3 invariant for 16-row wave-blocks.
__global__ __launch_bounds__(512) void gemm_splat(const f16* __restrict__ A,
                                                  const f16* __restrict__ Bt,
                                                  float* __restrict__ out) {
    __shared__ __attribute__((aligned(16))) f16 As[3 * 4096];   // [3][128][32]
    __shared__ __attribute__((aligned(16))) f16 Bs[3 * 4096];   // [3][128][32]

    int tid  = threadIdx.x;
    int lane = tid & 63;
    int w    = tid >> 6;                 // wave 0..7
    int wr   = w >> 1, wc = w & 1;       // wave -> (32-row, 64-col) quadrant
    // XCD-chunked bijective swizzle: 576 blocks = 8 XCDs x 72 (= 4 m-panels x 18 n-tiles)
    int bx   = blockIdx.x;
    int wg   = (bx & 7) * 72 + (bx >> 3);
    int m0   = (wg / 18) * 128;
    int tt   = wg % 18;
    int n0   = tt * 128;

    int k_lo, k_hi;
    kwindow(tt, k_lo, k_hi);
    int nt = (k_hi - k_lo) >> 5;

    // staging: wave w stages rows [w*16, w*16+16) of A and of B (1 gload16 each).
    // lane -> row w*16 + (lane>>2), chunk lane&3; source k-chunk pre-swizzled by
    // key (row>>1)&3 = (lane>>3)&3  (w*16 contributes 0 mod 4 to row>>1).
    int srow = lane >> 2;
    int sk   = (((lane & 3) ^ ((lane >> 3) & 3)) << 3);
    const f16* Abase = A  + (size_t)(m0 + w * 16 + srow) * KD + sk + k_lo;
    const f16* Bbase = Bt + (size_t)(n0 + w * 16 + srow) * KD + sk + k_lo;

    // fragment reads: row = 16*q + lrow; swizzled chunk = (lane>>4) ^ ((lrow>>1)&3)
    int lrow = lane & 15;
    int koe  = (((lane >> 4) ^ ((lane >> 1) & 3)) << 3);

    f32x4 acc[2][4] = {};

    // 2 gload16 per wave per stage -> counted wait vmcnt(2) keeps newest stage in flight
    #define STAGE(slot, koff)                                                   \
        do {                                                                    \
            gload16(Abase + (koff), &As[(slot) * 4096 + w * 512]);              \
            gload16(Bbase + (koff), &Bs[(slot) * 4096 + w * 512]);              \
        } while (0)

    // prologue: stage tiles 0,1; retire tile 0 (4 outstanding -> wait 2)
    STAGE(0, 0);
    STAGE(1, 32);
    asm volatile("s_waitcnt vmcnt(2)" ::: "memory");
    __builtin_amdgcn_s_barrier();
    __builtin_amdgcn_sched_barrier(0);

    int rs = 0, ps = 2;   // read slot t%3; stage slot (t+2)%3 == previous read slot
    for (int t = 0; t < nt; ++t) {
        if (t + 2 < nt) STAGE(ps, (t + 2) << 5);

        const f16* as_ = &As[rs * 4096];
        const f16* bs_ = &Bs[rs * 4096];
        f16x8 af[2], bf[4];
        #pragma unroll
        for (int mi = 0; mi < 2; ++mi)
            af[mi] = *(const f16x8*)&as_[(wr * 32 + mi * 16 + lrow) * 32 + koe];
        #pragma unroll
        for (int ni = 0; ni < 4; ++ni)
            bf[ni] = *(const f16x8*)&bs_[(wc * 64 + ni * 16 + lrow) * 32 + koe];

        __builtin_amdgcn_s_setprio(1);
        #pragma unroll
        for (int mi = 0; mi < 2; ++mi)
            #pragma unroll
            for (int ni = 0; ni < 4; ++ni)
                acc[mi][ni] = __builtin_amdgcn_mfma_f32_16x16x32_f16(af[mi], bf[ni], acc[mi][ni], 0, 0, 0);
        __builtin_amdgcn_s_setprio(0);

        // retire tile t+1 before the barrier; keep tile t+2's loads in flight
        if (t + 2 < nt) {
            asm volatile("s_waitcnt vmcnt(2)" ::: "memory");
        } else if (t + 1 < nt) {
            asm volatile("s_waitcnt vmcnt(0)" ::: "memory");
        }
        if (t + 1 < nt) {
            __builtin_amdgcn_s_barrier();
            __builtin_amdgcn_sched_barrier(0);
        }
        ps = rs;
        rs = (rs == 2) ? 0 : rs + 1;
    }
    #undef STAGE

    // epilogue: D row = (lane>>4)*4 + r, col = lane&15 (m89-verified C/D layout); clip + fold
    #pragma unroll
    for (int mi = 0; mi < 2; ++mi) {
        #pragma unroll
        for (int r = 0; r < 4; ++r) {
            int m  = m0 + wr * 32 + mi * 16 + (lane >> 4) * 4 + r;
            int bl = m >> 6, c = m & 63;
            int b  = bl >> 4, pr = (bl >> 2) & 3, pc = bl & 3;
            float* orow = out + ((size_t)(b * 64 + c) * HH + pr * 48) * HH + pc * 48;
            #pragma unroll
            for (int ni = 0; ni < 4; ++ni) {
                int n = n0 + wc * 64 + ni * 16 + (lane & 15);
                int y = n / 48, x = n - y * 48;
                float v = acc[mi][ni][r];
                v = fminf(fmaxf(v, 0.0f), 1.0f);
                orow[y * HH + x] = v;
            }
        }
    }
}

extern "C" void kernel_launch(void* const* d_in, const int* in_sizes, int n_in,
                              void* d_out, int out_size, void* d_ws, size_t ws_size,
                              hipStream_t stream) {
    const float* inp = (const float*)d_in[0];
    const float* sx  = (const float*)d_in[1];
    const float* sy  = (const float*)d_in[2];
    const float* op  = (const float*)d_in[3];
    float* out = (float*)d_out;

    char* ws = (char*)d_ws;
    f16* Kt = (f16*)ws;                      // 10616832 B  [2304][2304] (band rows only)
    f16* Ap = (f16*)(ws + 10616832);         // 18874368 B  [4096][2304]

    prep      <<<dim3(6192), dim3(256), 0, stream>>>(inp, sx, sy, op, Kt, Ap);
    gemm_splat<<<dim3(576),  dim3(512), 0, stream>>>(Ap, Kt, out);
}